// Round 1
// baseline (1789.193 us; speedup 1.0000x reference)
//
#include <hip/hip_runtime.h>
#include <math.h>

// Problem constants (fixed by reference)
#define B 128
#define R 36
#define VIS 2048
#define MM 1024
#define E 512
#define ATT 512
#define D 1024
#define V 10000
#define MAXLEN 20
#define T 19          // MAXLEN - 1
#define G4 4096       // 4*D

typedef unsigned short bf16_t;
typedef __attribute__((ext_vector_type(8))) short short8;
typedef __attribute__((ext_vector_type(4))) float f32x4;
typedef __attribute__((ext_vector_type(4))) unsigned short ushort4v;

__device__ __forceinline__ bf16_t f2bf(float f) {
    unsigned u = __float_as_uint(f);
    u += 0x7fff + ((u >> 16) & 1);   // round-to-nearest-even
    return (bf16_t)(u >> 16);
}
__device__ __forceinline__ float bf2f(bf16_t b) {
    return __uint_as_float(((unsigned)b) << 16);
}
__device__ __forceinline__ float sigmoidf_(float x) { return 1.0f / (1.0f + expf(-x)); }

// Async global->LDS, 16B per lane. LDS dest = wave-uniform base + lane*16.
__device__ __forceinline__ void stage16(const bf16_t* g, bf16_t* lds_wave_base, int lane) {
#if defined(__has_builtin) && __has_builtin(__builtin_amdgcn_global_load_lds)
    __builtin_amdgcn_global_load_lds(
        (const __attribute__((address_space(1))) void*)g,
        (__attribute__((address_space(3))) void*)lds_wave_base, 16, 0, 0);
#else
    *(short8*)(lds_wave_base + lane * 8) = *(const short8*)g;
#endif
}

// ---------------------------------------------------------------------------
// 128x128-tile bf16 MFMA GEMM, m97 structure.
// MODE 0: C[m*ldc+n] = acc (+bias)               (fp32 out)
// MODE 2: m = t*B+b; out[(b*T+t)*V+n] = mask ? acc+bias : 0
//         (grid SWAPPED: x = m-tiles, y = n-tiles, so consecutive blocks
//          share the same Wout n-tile -> better L2/L3 reuse)
//         Each m-tile is exactly one timestep t (B==128==tile height).
//         lengths sorted descending => valid rows are prefix [0,cnt).
//         Skip 16-row fragments that are fully masked; wave<->row-tile
//         mapping interleaved (rt = fm*2+wm) so the skip balances waves.
// MODE 3: bf16 out: ((bf16*)C)[m*ldc+n] = bf16(acc)
// ---------------------------------------------------------------------------
template<int MODE>
__global__ __launch_bounds__(256) void mfma_gemm_lds(
    const bf16_t* __restrict__ A, const bf16_t* __restrict__ W,
    const float* __restrict__ bias, const int* __restrict__ lengths,
    float* __restrict__ C, int M, int N, int K, int ldc)
{
    __shared__ __align__(16) bf16_t As[128 * 32];
    __shared__ __align__(16) bf16_t Ws[128 * 32];
    const int tid = threadIdx.x;
    const int wave = tid >> 6, lane = tid & 63;
    const int wm = wave >> 1, wn = wave & 1;
    const int quad = lane >> 4, l16 = lane & 15;
    const int m0 = (MODE == 2 ? blockIdx.x : blockIdx.y) * 128;
    const int n0 = (MODE == 2 ? blockIdx.y : blockIdx.x) * 128;

    int cnt = 128;
    if constexpr (MODE == 2) {
        const int tt = blockIdx.x;       // m-tile == timestep
        cnt = __syncthreads_count(tid < B && lengths[tid] > tt);
    }

    f32x4 acc[4][4];
    #pragma unroll
    for (int i = 0; i < 4; ++i)
        #pragma unroll
        for (int j = 0; j < 4; ++j)
            acc[i][j] = (f32x4){0.f, 0.f, 0.f, 0.f};

    for (int kk = 0; kk < K; kk += 32) {
        #pragma unroll
        for (int i = 0; i < 2; ++i) {
            int c = tid + i * 256;          // chunk 0..511
            int row = c >> 2, seg = c & 3;
            int m = m0 + row; if (m >= M) m = M - 1;
            stage16(A + (size_t)m * K + kk + seg * 8, &As[(i * 256 + wave * 64) * 8], lane);
            int n = n0 + row; if (n >= N) n = N - 1;
            stage16(W + (size_t)n * K + kk + seg * 8, &Ws[(i * 256 + wave * 64) * 8], lane);
        }
        __syncthreads();
        short8 af[4], bfr[4];
        #pragma unroll
        for (int fm = 0; fm < 4; ++fm) {
            const int rt = (MODE == 2) ? fm * 2 + wm : wm * 4 + fm;
            if (MODE != 2 || rt * 16 < cnt)
                af[fm] = *(const short8*)&As[(rt * 16 + l16) * 32 + quad * 8];
        }
        #pragma unroll
        for (int fn = 0; fn < 4; ++fn)
            bfr[fn] = *(const short8*)&Ws[(wn * 64 + fn * 16 + l16) * 32 + quad * 8];
        #pragma unroll
        for (int fm = 0; fm < 4; ++fm) {
            const int rt = (MODE == 2) ? fm * 2 + wm : wm * 4 + fm;
            if (MODE == 2 && rt * 16 >= cnt) continue;
            #pragma unroll
            for (int fn = 0; fn < 4; ++fn)
                acc[fm][fn] = __builtin_amdgcn_mfma_f32_16x16x32_bf16(
                    af[fm], bfr[fn], acc[fm][fn], 0, 0, 0);
        }
        __syncthreads();
    }

    #pragma unroll
    for (int fm = 0; fm < 4; ++fm) {
        const int rt = (MODE == 2) ? fm * 2 + wm : wm * 4 + fm;
        #pragma unroll
        for (int fn = 0; fn < 4; ++fn) {
            #pragma unroll
            for (int r = 0; r < 4; ++r) {
                int m = m0 + rt * 16 + quad * 4 + r;
                int n = n0 + wn * 64 + fn * 16 + l16;
                if (m >= M || n >= N) continue;
                float v = acc[fm][fn][r];
                if (MODE == 0) {
                    if (bias) v += bias[n];
                    C[(size_t)m * ldc + n] = v;
                } else if (MODE == 2) {
                    int t = m >> 7, b = m & 127;
                    v = (t < lengths[b]) ? (v + bias[n]) : 0.f;
                    C[((size_t)b * T + t) * V + n] = v;
                } else {
                    ((bf16_t*)C)[(size_t)m * ldc + n] = f2bf(v);
                }
            }
        }
    }
}

// ---------------------------------------------------------------------------
// Fused per-step attention + P-contraction:
//   t>0: ah = h@Wh^T, scores, softmax alpha;  t==0: alpha = 1/R uniform.
//   partial[b,n] = sum_r alpha[b,r] * P[b,r,n] + wordsW[t,b,n]
// P = visual @ Wih_v^T (precomputed, bf16). One block per b.
// ---------------------------------------------------------------------------
__global__ __launch_bounds__(256) void fused_att_p(
    const float* __restrict__ h, const bf16_t* __restrict__ Wh_bf,
    const float* __restrict__ att_fea, const float* __restrict__ att_bias,
    const float* __restrict__ Ww, const bf16_t* __restrict__ P_bf,
    const float* __restrict__ wordsW, float* __restrict__ partial, int t)
{
    int b = blockIdx.x, tid = threadIdx.x;
    __shared__ float hs[D];
    __shared__ float ah_s[ATT];
    __shared__ float sc_s[R];
    __shared__ float alpha_s[R];

    if (t > 0) {
        ((float4*)hs)[tid] = ((const float4*)(h + (size_t)b * D))[tid];
        __syncthreads();

        #pragma unroll 2
        for (int a = tid; a < ATT; a += 256) {
            const bf16_t* wrow = Wh_bf + (size_t)a * D;
            float s = 0.f;
            for (int k = 0; k < D; k += 8) {
                short8 wv = *(const short8*)(wrow + k);
                float4 ha = *(const float4*)&hs[k];
                float4 hb = *(const float4*)&hs[k + 4];
                s = fmaf(bf2f((bf16_t)wv[0]), ha.x, s);
                s = fmaf(bf2f((bf16_t)wv[1]), ha.y, s);
                s = fmaf(bf2f((bf16_t)wv[2]), ha.z, s);
                s = fmaf(bf2f((bf16_t)wv[3]), ha.w, s);
                s = fmaf(bf2f((bf16_t)wv[4]), hb.x, s);
                s = fmaf(bf2f((bf16_t)wv[5]), hb.y, s);
                s = fmaf(bf2f((bf16_t)wv[6]), hb.z, s);
                s = fmaf(bf2f((bf16_t)wv[7]), hb.w, s);
            }
            ah_s[a] = s;
        }
        __syncthreads();

        int wave = tid >> 6, lane = tid & 63;
        for (int r = wave; r < R; r += 4) {
            float ab = att_bias[r];
            const float* af = att_fea + ((size_t)b * R + r) * ATT;
            float s = 0.f;
            for (int a = lane; a < ATT; a += 64) {
                float v = af[a] + ah_s[a] + ab;
                s = fmaf(fmaxf(v, 0.f), Ww[a], s);
            }
            #pragma unroll
            for (int off = 32; off; off >>= 1) s += __shfl_down(s, off);
            if (lane == 0) sc_s[r] = s;
        }
        __syncthreads();

        if (tid < 64) {
            float v = (tid < R) ? sc_s[tid] : -INFINITY;
            float m = v;
            #pragma unroll
            for (int off = 32; off; off >>= 1) m = fmaxf(m, __shfl_down(m, off));
            m = __shfl(m, 0);
            float e = (tid < R) ? expf(v - m) : 0.f;
            float ss = e;
            #pragma unroll
            for (int off = 32; off; off >>= 1) ss += __shfl_down(ss, off);
            ss = __shfl(ss, 0);
            if (tid < R) alpha_s[tid] = e / ss;
        }
    } else {
        if (tid < R) alpha_s[tid] = 1.0f / R;
    }
    __syncthreads();

    // partial[b, n0:n0+16] = sum_r alpha[r] * P[b,r,n0:16] + wordsW[t,b,n0:16]
    const int n0 = tid * 16;                 // 256 * 16 = 4096 = G4
    float acc[16];
    #pragma unroll
    for (int j = 0; j < 16; ++j) acc[j] = 0.f;
    const bf16_t* Pb = P_bf + (size_t)b * R * G4 + n0;
    #pragma unroll 4
    for (int r = 0; r < R; ++r) {
        float al = alpha_s[r];
        short8 p0 = *(const short8*)(Pb + (size_t)r * G4);
        short8 p1 = *(const short8*)(Pb + (size_t)r * G4 + 8);
        #pragma unroll
        for (int j = 0; j < 8; ++j) {
            acc[j]     = fmaf(al, bf2f((bf16_t)p0[j]), acc[j]);
            acc[8 + j] = fmaf(al, bf2f((bf16_t)p1[j]), acc[8 + j]);
        }
    }
    const float* wsl = wordsW + ((size_t)t * B + b) * G4 + n0;
    float* po = partial + (size_t)b * G4 + n0;
    #pragma unroll
    for (int j = 0; j < 16; j += 4) {
        float4 w = *(const float4*)(wsl + j);
        float4 o = { acc[j] + w.x, acc[j + 1] + w.y, acc[j + 2] + w.z, acc[j + 3] + w.w };
        *(float4*)(po + j) = o;
    }
}

// ---------------------------------------------------------------------------
// Per-step h-GEMM + LSTM pointwise (K = D = 1024; visual part is in
// `partial`). Block (blockIdx.x = d-tile of 8, blockIdx.y = m-tile of 64)
// computes the 32 gathered gate columns {g*D+d0+r} for 64 batch rows.
//
// Restructured: the 32 gathered Whh rows x full K (64KB) are staged into
// LDS ONCE (single barrier), laid out read-major so ds_read_b128 is
// conflict-free. A-fragments are read directly global->VGPR (h is 256KB,
// L2-resident). The K-loop is barrier-free and unrolled, so global-load
// latency is hidden by compiler pipelining instead of being exposed 32x
// behind per-K-step __syncthreads drains.
// h ping-pong: h_in and h_out are DISTINCT buffers (race-free).
// ---------------------------------------------------------------------------
__global__ __launch_bounds__(256) void gates_lstm(
    const bf16_t* __restrict__ h_in,    // B x D bf16 (step t-1)
    const bf16_t* __restrict__ Whh,     // G4 x D
    const float* __restrict__ bih, const float* __restrict__ bhh,
    const float* __restrict__ partial,  // B x G4 (alpha.P + wordsW[t])
    const int* __restrict__ lengths,
    float* __restrict__ c_st,           // B x D fp32 (in/out)
    float* __restrict__ h_f32,          // B x D fp32 (in/out, for attention)
    bf16_t* __restrict__ h_out,         // B x D bf16 (step t)
    bf16_t* __restrict__ hseq,          // (t*B+m)*D
    int t)
{
    // Ws layout: 16B chunk c holds Whh[rowv(c&31)][(c>>5)*8 .. +8]
    // i.e. [qk 0..127][row 0..31][8 elems]  (read-major => conflict-free b128)
    __shared__ __align__(16) bf16_t Ws[32 * 1024];   // 64 KB
    const int tid = threadIdx.x;
    const int wave = tid >> 6, lane = tid & 63;
    const int quad = lane >> 4, l16 = lane & 15;
    const int d0 = blockIdx.x * 8;
    const int m0 = blockIdx.y * 64;
    const int gsel_ = l16 >> 3, dr = l16 & 7;

    // ---- one-shot staging of the whole gathered W slab ----
    #pragma unroll
    for (int i = 0; i < 16; ++i) {
        int c = i * 256 + tid;               // chunk 0..4095
        int row = c & 31, qk = c >> 5;       // row: gathered Whh row, qk: 8-elem k-slot
        int rv = (row >> 3) * D + d0 + (row & 7);
        stage16(Whh + (size_t)rv * D + qk * 8, &Ws[(i * 256 + wave * 64) * 8], lane);
    }

    const bf16_t* Ar = h_in + (size_t)(m0 + wave * 16 + l16) * D + quad * 8;

    f32x4 acc0 = (f32x4){0.f, 0.f, 0.f, 0.f};
    f32x4 acc1 = (f32x4){0.f, 0.f, 0.f, 0.f};
    __syncthreads();                          // drains vmcnt for global_load_lds

    #pragma unroll 8
    for (int kt = 0; kt < 32; ++kt) {
        short8 af = *(const short8*)(Ar + kt * 32);
        const int cb = (kt * 4 + quad) * 32 * 8;   // element base for (kt,quad)
        short8 b0 = *(const short8*)&Ws[cb + l16 * 8];
        short8 b1 = *(const short8*)&Ws[cb + (16 + l16) * 8];
        acc0 = __builtin_amdgcn_mfma_f32_16x16x32_bf16(af, b0, acc0, 0, 0, 0);
        acc1 = __builtin_amdgcn_mfma_f32_16x16x32_bf16(af, b1, acc1, 0, 0, 0);
    }

    const int d = d0 + dr;
    const int col0 = gsel_ * D + d;
    const int col1 = (2 + gsel_) * D + d;
    const float bia0 = bih[col0] + bhh[col0];
    const float bia1 = bih[col1] + bhh[col1];

    #pragma unroll
    for (int r = 0; r < 4; ++r) {
        int m = m0 + wave * 16 + quad * 4 + r;
        size_t pb = (size_t)m * G4;
        float v0 = acc0[r] + bia0 + partial[pb + col0];
        float v1 = acc1[r] + bia1 + partial[pb + col1];
        float w0 = __shfl_xor(v0, 8);
        float w1 = __shfl_xor(v1, 8);
        float iv, fv, gv, ov;
        if (gsel_ == 0) { iv = v0; gv = v1; fv = w0; ov = w1; }
        else            { fv = v0; ov = v1; iv = w0; gv = w1; }
        float ig = sigmoidf_(iv), fg = sigmoidf_(fv);
        float gg = tanhf(gv),     og = sigmoidf_(ov);
        size_t off = (size_t)m * D + d;
        if (gsel_ == 0) {
            float c_old = c_st[off];
            float h_old = h_f32[off];
            float cn = fmaf(fg, c_old, ig * gg);
            float hn = og * tanhf(cn);
            bool msk = t < lengths[m];
            float cv = msk ? cn : c_old;
            float hv = msk ? hn : h_old;
            c_st[off] = cv;
            h_f32[off] = hv;
            bf16_t hb = f2bf(hv);
            h_out[off] = hb;
            hseq[((size_t)t * B + m) * D + d] = hb;
        }
    }
}

// Strided fp32 -> bf16 cast
__global__ __launch_bounds__(256) void cast_bf16_k(
    const float* __restrict__ src, bf16_t* __restrict__ dst,
    int rows, int cols, int ld)
{
    int idx = blockIdx.x * 256 + threadIdx.x;
    int total = rows * (cols >> 2);
    if (idx >= total) return;
    int cq = cols >> 2;
    int r = idx / cq, c4 = (idx - r * cq) * 4;
    float4 v = *(const float4*)(src + (size_t)r * ld + c4);
    ushort4v o = { f2bf(v.x), f2bf(v.y), f2bf(v.z), f2bf(v.w) };
    *(ushort4v*)(dst + (size_t)r * cols + c4) = o;
}

// words_bf[(t*B+b)*E + :] = bf16(embed_W[captions[b][t]][:])
__global__ __launch_bounds__(128) void embed_k(
    const int* __restrict__ captions, const float* __restrict__ embed_W,
    bf16_t* __restrict__ words_bf)
{
    int bt = blockIdx.x;
    int b = bt / T, t = bt - b * T;
    int tok = captions[b * MAXLEN + t];
    int i = threadIdx.x * 4;
    float4 v = *(const float4*)(embed_W + (size_t)tok * E + i);
    ushort4v o = { f2bf(v.x), f2bf(v.y), f2bf(v.z), f2bf(v.w) };
    *(ushort4v*)(words_bf + ((size_t)t * B + b) * E + i) = o;
}

extern "C" void kernel_launch(void* const* d_in, const int* in_sizes, int n_in,
                              void* d_out, int out_size, void* d_ws, size_t ws_size,
                              hipStream_t stream) {
    const float* visual   = (const float*)d_in[0];
    const float* joint    = (const float*)d_in[1];
    const int*   captions = (const int*)d_in[2];
    const int*   lengths  = (const int*)d_in[3];
    const float* embed_W  = (const float*)d_in[5];
    const float* Wih      = (const float*)d_in[6];
    const float* bih      = (const float*)d_in[7];
    const float* Whh      = (const float*)d_in[8];
    const float* bhh      = (const float*)d_in[9];
    const float* W_init_h = (const float*)d_in[10];
    const float* b_init_h = (const float*)d_in[11];
    const float* W_init_c = (const float*)d_in[12];
    const float* b_init_c = (const float*)d_in[13];
    const float* Wv       = (const float*)d_in[14];
    const float* Wh       = (const float*)d_in[15];
    const float* att_bias = (const float*)d_in[16];
    const float* Ww       = (const float*)d_in[17];
    const float* Wout     = (const float*)d_in[18];
    const float* bout     = (const float*)d_in[19];
    float* out = (float*)d_out;

    // ---- workspace carve-up ----
    char* cur = (char*)d_ws;
    auto alloc = [&](size_t bytes) { char* p = cur; cur += (bytes + 15) & ~size_t(15); return p; };
    float*  att_fea  = (float*)alloc((size_t)B * R * ATT * 4);       // 9.4 MB
    float*  wordsW   = (float*)alloc((size_t)T * B * G4 * 4);        // 39.8 MB
    float*  partial  = (float*)alloc((size_t)B * G4 * 4);            // 2.1 MB
    float*  hf       = (float*)alloc((size_t)B * D * 4);
    float*  c_st     = (float*)alloc((size_t)B * D * 4);
    bf16_t* words_bf = (bf16_t*)alloc((size_t)T * B * E * 2);
    bf16_t* h_ping0  = (bf16_t*)alloc((size_t)B * D * 2);
    bf16_t* h_ping1  = (bf16_t*)alloc((size_t)B * D * 2);
    bf16_t* hseq_bf  = (bf16_t*)alloc((size_t)T * B * D * 2);        // 5 MB
    bf16_t* P_bf     = (bf16_t*)alloc((size_t)B * R * G4 * 2);       // 37.7 MB
    bf16_t* visual_bf= (bf16_t*)alloc((size_t)B * R * VIS * 2);      // 18.9 MB
    bf16_t* Wv_bf    = (bf16_t*)alloc((size_t)ATT * VIS * 2);
    bf16_t* Wh_bf    = (bf16_t*)alloc((size_t)ATT * D * 2);
    bf16_t* Whh_bf   = (bf16_t*)alloc((size_t)G4 * D * 2);
    bf16_t* Wih_v_bf = (bf16_t*)alloc((size_t)G4 * VIS * 2);
    bf16_t* Wih_w_bf = (bf16_t*)alloc((size_t)G4 * E * 2);
    bf16_t* Wout_bf  = (bf16_t*)alloc((size_t)V * D * 2);
    bf16_t* joint_bf = (bf16_t*)alloc((size_t)B * MM * 2);
    bf16_t* Winh_bf  = (bf16_t*)alloc((size_t)D * MM * 2);
    bf16_t* Winc_bf  = (bf16_t*)alloc((size_t)D * MM * 2);

    auto cast = [&](const float* s, bf16_t* dst, int rows, int cols, int ld) {
        int total = rows * (cols >> 2);
        cast_bf16_k<<<(total + 255) / 256, 256, 0, stream>>>(s, dst, rows, cols, ld);
    };
    cast(visual, visual_bf, 1, B * R * VIS, B * R * VIS);
    cast(Wv,  Wv_bf,  ATT, VIS, VIS);
    cast(Wh,  Wh_bf,  ATT, D, D);
    cast(Whh, Whh_bf, G4, D, D);
    cast(Wih, Wih_v_bf, G4, VIS, VIS + E);
    cast(Wih + VIS, Wih_w_bf, G4, E, VIS + E);
    cast(Wout, Wout_bf, V, D, D);
    cast(joint, joint_bf, 1, B * MM, B * MM);
    cast(W_init_h, Winh_bf, 1, D * MM, D * MM);
    cast(W_init_c, Winc_bf, 1, D * MM, D * MM);

    embed_k<<<B * T, 128, 0, stream>>>(captions, embed_W, words_bf);

    // h0/c0 seed via MFMA (was a 32-block fp32 VALU tile GEMM)
    mfma_gemm_lds<0><<<dim3(D / 128, B / 128), 256, 0, stream>>>(
        joint_bf, Winh_bf, b_init_h, nullptr, hf, B, D, MM, D);
    mfma_gemm_lds<0><<<dim3(D / 128, B / 128), 256, 0, stream>>>(
        joint_bf, Winc_bf, b_init_c, nullptr, c_st, B, D, MM, D);
    cast(hf, h_ping0, 1, B * D, B * D);

    // att_fea = visual @ Wv^T (fp32 out)
    mfma_gemm_lds<0><<<dim3(ATT / 128, (B * R) / 128), 256, 0, stream>>>(
        visual_bf, Wv_bf, nullptr, nullptr, att_fea, B * R, ATT, VIS, ATT);

    // wordsW = words @ Wih_w^T (all steps)
    mfma_gemm_lds<0><<<dim3(G4 / 128, (T * B) / 128), 256, 0, stream>>>(
        words_bf, Wih_w_bf, nullptr, nullptr, wordsW, T * B, G4, E, G4);

    // P = visual @ Wih_v^T (bf16 out)  -- the key precompute: the visual
    // part of the gates becomes a per-step alpha-weighted sum over P rows.
    mfma_gemm_lds<3><<<dim3(G4 / 128, (B * R) / 128), 256, 0, stream>>>(
        visual_bf, Wih_v_bf, nullptr, nullptr, (float*)P_bf, B * R, G4, VIS, G4);

    // ---- recurrence (h bf16 ping-pong) ----
    bf16_t* h_buf[2] = { h_ping0, h_ping1 };
    for (int t = 0; t < T; ++t) {
        fused_att_p<<<B, 256, 0, stream>>>(
            hf, Wh_bf, att_fea, att_bias, Ww, P_bf, wordsW, partial, t);
        gates_lstm<<<dim3(D / 8, B / 64), 256, 0, stream>>>(
            h_buf[t & 1], Whh_bf, bih, bhh, partial, lengths,
            c_st, hf, h_buf[(t + 1) & 1], hseq_bf, t);
    }

    // ---- deferred vocab projection (grid swapped: x=m-tiles, y=n-tiles) ----
    mfma_gemm_lds<2><<<dim3((T * B) / 128, (V + 127) / 128), 256, 0, stream>>>(
        hseq_bf, Wout_bf, bout, lengths, out, T * B, V, D, V);
}